// Round 19
// baseline (3255.817 us; speedup 1.0000x reference)
//
#include <hip/hip_runtime.h>
#include <hip/hip_bf16.h>

typedef __hip_bfloat16 bf16;
typedef __attribute__((ext_vector_type(8))) short short8;
typedef __attribute__((ext_vector_type(4))) float f32x4;

#define T_ 256
#define B_ 64
#define V_ 10000
#define E_ 400
#define H_ 1152
#define KU 2304      // uniform padded K for weight buffers (72 kt of 32)
#define XW 416       // padded embedding width (13 kt)
#define KD 416       // decoder K (padded)
#define XET (XW*B_)  // shorts per timestep in frag-major
#define NBLK 169

#define MFMA16 __builtin_amdgcn_mfma_f32_16x16x32_bf16
#define ATL(p) __hip_atomic_load((p), __ATOMIC_RELAXED, __HIP_MEMORY_SCOPE_AGENT)
#define ATS(p, v) __hip_atomic_store((p), (v), __ATOMIC_RELAXED, __HIP_MEMORY_SCOPE_AGENT)
#define PIN(x) asm volatile("" : "+v"(x))

// ---------------- prep kernels ----------------

// 8-wide gate-interleaved weight prep (region boundaries all %8 == 0)
__global__ __launch_bounds__(256) void prep_wint8(
    const float* __restrict__ s1, int w1,
    const float* __restrict__ s2, int off2, int w2, int Hl,
    bf16* __restrict__ dst, long total8)
{
    long i = (long)blockIdx.x * 256 + threadIdx.x;
    if (i >= total8) return;
    const int KB = KU / 8;
    int kb = (int)(i % KB) * 8;
    long r = i / KB;
    int hcol = (int)(r >> 2), gate = (int)(r & 3);
    long srow = (long)gate * Hl + hcol;
    const float* src = nullptr;
    if (kb < w1) src = s1 + srow * w1 + kb;
    else if (kb >= off2 && kb < off2 + w2) src = s2 + srow * w2 + (kb - off2);
    short8 v;
    #pragma unroll
    for (int j = 0; j < 8; ++j) {
        bf16 b = __float2bfloat16(src ? src[j] : 0.f);
        unsigned short us; __builtin_memcpy(&us, &b, 2);
        v[j] = (short)us;
    }
    *(short8*)(dst + r * KU + kb) = v;
}

// 8-wide decoder weight prep (w1=400 multiple of 8)
__global__ __launch_bounds__(256) void prep_wcat8(
    const float* __restrict__ s1, int w1,
    bf16* __restrict__ dst, int Ktot, long total8)
{
    long i = (long)blockIdx.x * 256 + threadIdx.x;
    if (i >= total8) return;
    int KB = Ktot / 8;
    int kb = (int)(i % KB) * 8;
    long n = i / KB;
    const float* src = (kb < w1) ? s1 + n * w1 + kb : nullptr;
    short8 v;
    #pragma unroll
    for (int j = 0; j < 8; ++j) {
        bf16 b = __float2bfloat16(src ? src[j] : 0.f);
        unsigned short us; __builtin_memcpy(&us, &b, 2);
        v[j] = (short)us;
    }
    *(short8*)(dst + n * Ktot + kb) = v;
}

// fused bias prep
__global__ __launch_bounds__(256) void bias_all(
    const float* __restrict__ bih0, const float* __restrict__ bhh0,
    const float* __restrict__ bih1, const float* __restrict__ bhh1,
    const float* __restrict__ bih2, const float* __restrict__ bhh2,
    float* __restrict__ b0i, float* __restrict__ b1i, float* __restrict__ b2i)
{
    int i = blockIdx.x * 256 + threadIdx.x;
    if (i < 4608) {
        int hcol = i >> 2, g = i & 3;
        b0i[i] = bih0[g * 1152 + hcol] + bhh0[g * 1152 + hcol];
    } else if (i < 9216) {
        int r = i - 4608, hcol = r >> 2, g = r & 3;
        b1i[r] = bih1[g * 1152 + hcol] + bhh1[g * 1152 + hcol];
    } else if (i < 10816) {
        int r = i - 9216, hcol = r >> 2, g = r & 3;
        b2i[r] = bih2[g * 400 + hcol] + bhh2[g * 400 + hcol];
    }
}

// 8-wide embeddings -> frag-major bf16
__global__ __launch_bounds__(256) void gather_xef8(
    const int* __restrict__ x, const float* __restrict__ emb,
    bf16* __restrict__ XEf)
{
    long i = (long)blockIdx.x * 256 + threadIdx.x;
    const long total8 = (long)T_ * B_ * (XW / 8);
    if (i >= total8) return;
    const int KB = XW / 8;
    int kb = (int)(i % KB) * 8;
    int b = (int)((i / KB) % B_);
    int t = (int)(i / ((long)KB * B_));
    const float* src = (kb < E_) ? emb + (long)x[t * B_ + b] * E_ + kb : nullptr;
    short8 v;
    #pragma unroll
    for (int j = 0; j < 8; ++j) {
        bf16 bb = __float2bfloat16(src ? src[j] : 0.f);
        unsigned short us; __builtin_memcpy(&us, &bb, 2);
        v[j] = (short)us;
    }
    *(short8*)(XEf + (long)t * XET + (((kb >> 3) * 64 + b) << 3)) = v;
}

// fused state init
__global__ __launch_bounds__(256) void init_states(
    const float* __restrict__ h0, const float* __restrict__ h1,
    const float* __restrict__ h2,
    const float* __restrict__ c0, const float* __restrict__ c1,
    const float* __restrict__ c2,
    bf16* __restrict__ H0f1, bf16* __restrict__ H1f1,
    bf16* __restrict__ H2f0, bf16* __restrict__ H2f1,
    float* __restrict__ c0b, float* __restrict__ c1b, float* __restrict__ c2b,
    int* __restrict__ gbar)
{
    int i = blockIdx.x * 256 + threadIdx.x;
    if (i < B_ * H_) {
        int k = ((i >> 9) << 3) | (i & 7);
        int b = (i >> 3) & 63;
        H0f1[i] = __float2bfloat16(h0[(long)b * H_ + k]);
        H1f1[i] = __float2bfloat16(h1[(long)b * H_ + k]);
        c0b[i] = c0[i];
        c1b[i] = c1[i];
    }
    if (i < B_ * XW) {
        int k = ((i >> 9) << 3) | (i & 7);
        int b = (i >> 3) & 63;
        H2f1[i] = (k < E_) ? __float2bfloat16(h2[(long)b * E_ + k])
                           : __float2bfloat16(0.f);
        H2f0[i] = __float2bfloat16(0.f);
    }
    if (i < B_ * E_) c2b[i] = c2[i];
    if (i < 512) gbar[i] = 0;
}

// ---- two-level grid barrier with 8-way replicated gen publication ----
__device__ __forceinline__ void grid_bar(int* flags, int* gen8, int phase) {
    asm volatile("s_waitcnt vmcnt(0)" ::: "memory");  // per-wave: stores drained
    __syncthreads();
    if (blockIdx.x == 0) {
        if (threadIdx.x < 64) {
            const int ln = threadIdx.x;
            if (ln == 0) ATS(&flags[0], phase);
            for (;;) {
                int f0 = (ln       < NBLK) ? ATL(&flags[ln])       : phase;
                int f1 = (ln + 64  < NBLK) ? ATL(&flags[ln + 64])  : phase;
                int f2 = (ln + 128 < NBLK) ? ATL(&flags[ln + 128]) : phase;
                if (__all(f0 >= phase && f1 >= phase && f2 >= phase)) break;
                __builtin_amdgcn_s_sleep(1);
            }
            if (ln < 8) ATS(&gen8[ln * 16], phase);
            if (ln == 0)
                __builtin_amdgcn_fence(__ATOMIC_ACQUIRE, "agent");  // inv L1/L2
        }
    } else {
        if (threadIdx.x == 0) {
            ATS(&flags[blockIdx.x], phase);
            while (ATL(&gen8[(blockIdx.x & 7) * 16]) < phase)
                __builtin_amdgcn_s_sleep(1);
            __builtin_amdgcn_fence(__ATOMIC_ACQUIRE, "agent");      // inv L1/L2
        }
    }
    __syncthreads();
    asm volatile("" ::: "memory");
}

// ------------- weight-stationary persistent LSTM (R14 structure,
//               + 2-deep B-frag load pipeline) -------------
struct Frag4 { short8 f0, f1, f2, f3; };

__global__ __launch_bounds__(512, 2) void awd_persistent(
    const bf16* __restrict__ XEf,
    const bf16* __restrict__ W0, const bf16* __restrict__ W1, const bf16* __restrict__ W2,
    const float* __restrict__ b0, const float* __restrict__ b1, const float* __restrict__ b2,
    bf16* H0f0, bf16* H0f1, bf16* H1f0, bf16* H1f1, bf16* H2f0, bf16* H2f1,
    float* c0, float* c1, float* c2, bf16* OUTB,
    int* flags, int* gen8)
{
    __shared__ float gsm[2][4][64][65];     // 133 KB: two halves, no RMW pass
    __shared__ unsigned short hsm[64][24];  // h transpose buffer
    const int bid = blockIdx.x;
    const int tid = threadIdx.x;
    const int lane = tid & 63;
    const int w8 = tid >> 6;              // K-slice index 0..7
    const int lh = lane >> 4, l15 = lane & 15;
    const int boff8 = (lh * 64 + l15) * 8;

    int layer, grp;
    if (bid < 72)       { layer = 1; grp = bid; }
    else if (bid < 144) { layer = 0; grp = bid - 72; }
    else                { layer = 2; grp = bid - 144; }

    const bf16* Wp  = (layer == 0) ? W0 : (layer == 1) ? W1 : W2;
    const float* bias = (layer == 0) ? b0 : (layer == 1) ? b1 : b2;
    const float* cbuf = (layer == 0) ? c0 : (layer == 1) ? c1 : c2;
    const int Hl  = (layer == 2) ? 400 : 1152;
    const int bkt = (layer == 0) ? 13 : 36;   // kt where A switches A1 -> A2
    const int nkt = (layer == 1) ? 72 : 49;   // real kt count
    const int KT  = (layer == 1) ? 9  : 7;    // u-steps per wave
    const int kbase = w8 * KT;

    // ---- weights into registers (once), then PIN so they stay resident ----
    short8 wreg[9][4];
    #pragma unroll
    for (int u = 0; u < 9; ++u)
        if (u < KT) {
            #pragma unroll
            for (int rt = 0; rt < 4; ++rt) {
                int row = grp * 64 + rt * 16 + l15;
                int k   = (kbase + u) * 32 + lh * 8;
                wreg[u][rt] = *(const short8*)(Wp + (long)row * KU + k);
                PIN(wreg[u][rt]);
            }
        }

    float myb[2][4];
    #pragma unroll
    for (int e = 0; e < 2; ++e)
        #pragma unroll
        for (int g = 0; g < 4; ++g)
            myb[e][g] = bias[grp * 64 + (w8 + e * 8) * 4 + g];

    float creg[2];
    #pragma unroll
    for (int e = 0; e < 2; ++e)
        creg[e] = cbuf[(long)lane * Hl + grp * 16 + w8 + e * 8];

    for (int s = -1; s <= 256; ++s) {
        bool active = (layer == 0) ? (s <= 254)
                    : (layer == 1) ? (s >= 0 && s <= 255)
                                   : (s >= 1);
        if (active) {
            const int p = s & 1, q = p ^ 1;
            const bf16 *A1, *A2; bf16* hfW; bf16* ob = nullptr;
            if (layer == 0) {
                A1 = XEf + (long)(s + 1) * XET;
                A2 = p ? H0f1 : H0f0;
                hfW = q ? H0f1 : H0f0;
            } else if (layer == 1) {
                A1 = p ? H0f1 : H0f0;
                A2 = q ? H1f1 : H1f0;
                hfW = p ? H1f1 : H1f0;
            } else {
                A1 = q ? H1f1 : H1f0;
                A2 = p ? H2f1 : H2f0;
                hfW = q ? H2f1 : H2f0;
                ob = OUTB + (long)(s - 1) * B_ * XW;
            }

            // plain CACHED frag load; frags at +0,+128,+256,+384 bf16 elements
            auto loadf = [&](int u) -> Frag4 {
                const int ktg = kbase + u;
                const bf16* src; int ktL;
                if (ktg < bkt)      { src = A1; ktL = ktg; }
                else if (ktg < nkt) { src = A2; ktL = ktg - bkt; }
                else                { src = A1; ktL = 0; }   // pad: zero weights
                const bf16* pB = src + ktL * 2048 + boff8;
                Frag4 r;
                r.f0 = *(const short8*)(pB);
                r.f1 = *(const short8*)(pB + 128);
                r.f2 = *(const short8*)(pB + 256);
                r.f3 = *(const short8*)(pB + 384);
                return r;
            };

            f32x4 acc[4][4];
            #pragma unroll
            for (int rt = 0; rt < 4; ++rt)
                #pragma unroll
                for (int m = 0; m < 4; ++m)
                    acc[rt][m] = (f32x4){0.f, 0.f, 0.f, 0.f};

            auto domfma = [&](int u, const Frag4& f) {
                #pragma unroll
                for (int rt = 0; rt < 4; ++rt) {
                    acc[rt][0] = MFMA16(wreg[u][rt], f.f0, acc[rt][0], 0, 0, 0);
                    acc[rt][1] = MFMA16(wreg[u][rt], f.f1, acc[rt][1], 0, 0, 0);
                    acc[rt][2] = MFMA16(wreg[u][rt], f.f2, acc[rt][2], 0, 0, 0);
                    acc[rt][3] = MFMA16(wreg[u][rt], f.f3, acc[rt][3], 0, 0, 0);
                }
            };

            // 2-deep load pipeline: load(u+1) in flight while computing u
            {
                Frag4 cur = loadf(0);
                #pragma unroll
                for (int u = 0; u < 9; ++u)
                    if (u < KT) {
                        Frag4 nxt = cur;
                        if (u + 1 < KT) nxt = loadf(u + 1);
                        domfma(u, cur);
                        cur = nxt;
                    }
            }

            // dual-buffer merge: all 8 waves write in parallel
            #pragma unroll
            for (int rt = 0; rt < 4; ++rt)
                #pragma unroll
                for (int m = 0; m < 4; ++m)
                    #pragma unroll
                    for (int r = 0; r < 4; ++r)
                        gsm[w8 >> 2][w8 & 3][rt * 16 + lh * 4 + r][m * 16 + l15] = acc[rt][m][r];
            __syncthreads();

            // nonlinearity: 16 cols x 64 batch, 2 per thread; h -> LDS transpose
            #pragma unroll
            for (int e = 0; e < 2; ++e) {
                int b = lane;
                int cl = w8 + e * 8;
                float gv[4];
                #pragma unroll
                for (int g = 0; g < 4; ++g) {
                    float v = myb[e][g];
                    #pragma unroll
                    for (int kq = 0; kq < 4; ++kq)
                        v += gsm[0][kq][cl * 4 + g][b] + gsm[1][kq][cl * 4 + g][b];
                    gv[g] = v;
                }
                float c_old = creg[e];
                float i_s = 1.f / (1.f + expf(-gv[0]));
                float f_s = 1.f / (1.f + expf(-gv[1]));
                float o_s = 1.f / (1.f + expf(-gv[3]));
                float c_new = f_s * c_old + i_s * tanhf(gv[2]);
                float hval = o_s * tanhf(c_new);
                creg[e] = c_new;
                bf16 hb = __float2bfloat16(hval);
                unsigned short hbits;
                __builtin_memcpy(&hbits, &hb, 2);
                hsm[b][cl] = hbits;
            }
            __syncthreads();

            // coalesced store-out: waves 0/1 -> h frag-major (write-through,
            // 16B/lane); wave 2 -> OUTB
            if (w8 < 2) {
                unsigned long long v0, v1;
                __builtin_memcpy(&v0, &hsm[lane][w8 * 8], 8);
                __builtin_memcpy(&v1, &hsm[lane][w8 * 8 + 4], 8);
                unsigned long long* qp =
                    (unsigned long long*)(hfW + (((long)grp * 2 + w8) * 64 + lane) * 8);
                ATS(qp, v0);
                ATS(qp + 1, v1);
            } else if (w8 == 2 && layer == 2) {
                short8 v0 = *(const short8*)&hsm[lane][0];
                short8 v1 = *(const short8*)&hsm[lane][8];
                *(short8*)(ob + (long)lane * XW + grp * 16) = v0;
                *(short8*)(ob + (long)lane * XW + grp * 16 + 8) = v1;
            }
        }
        grid_bar(flags, gen8, s + 2);
    }
}

// ---------------- decoder GEMM: 128x128 per WG, XCD N-stripe swizzle ----------------
__global__ __launch_bounds__(256) void decoder(
    const bf16* __restrict__ A, const bf16* __restrict__ W,
    const float* __restrict__ bias, float* __restrict__ out)
{
    const int id = blockIdx.x;
    const int xcd = id & 7;
    const int local = id >> 3;
    const int n_blk = xcd * 10 + local % 10;
    const int m_blk = local / 10;
    if (n_blk >= 79) return;

    const int tid = threadIdx.x;
    const int lane = tid & 63;
    const int w = tid >> 6;
    const int mw = w >> 1, nw = w & 1;
    const int n0 = n_blk * 128 + nw * 64;
    const int m0 = m_blk * 128 + mw * 64;
    const int c16 = lane & 15;
    const int kg = lane >> 4;

    f32x4 acc[4][4];
    #pragma unroll
    for (int mi = 0; mi < 4; ++mi)
        #pragma unroll
        for (int ns = 0; ns < 4; ++ns)
            acc[mi][ns] = (f32x4){0.f, 0.f, 0.f, 0.f};

    int nrow[4];
    #pragma unroll
    for (int ns = 0; ns < 4; ++ns) {
        int n = n0 + ns * 16 + c16;
        nrow[ns] = (n < V_) ? n : (V_ - 1);
    }

    const bf16* arow = A + (long)(m0 + c16) * KD + kg * 8;
    #pragma unroll
    for (int kt = 0; kt < 13; ++kt) {
        short8 af[4], bf[4];
        #pragma unroll
        for (int mi = 0; mi < 4; ++mi)
            af[mi] = *(const short8*)(arow + (long)mi * 16 * KD + kt * 32);
        #pragma unroll
        for (int ns = 0; ns < 4; ++ns)
            bf[ns] = *(const short8*)(W + (long)nrow[ns] * KD + kt * 32 + kg * 8);
        #pragma unroll
        for (int mi = 0; mi < 4; ++mi)
            #pragma unroll
            for (int ns = 0; ns < 4; ++ns)
                acc[mi][ns] = MFMA16(af[mi], bf[ns], acc[mi][ns], 0, 0, 0);
    }

    #pragma unroll
    for (int mi = 0; mi < 4; ++mi)
        #pragma unroll
        for (int ns = 0; ns < 4; ++ns) {
            int col = n0 + ns * 16 + c16;
            if (col < V_) {
                float bv = bias[col];
                #pragma unroll
                for (int r = 0; r < 4; ++r) {
                    int row = m0 + mi * 16 + kg * 4 + r;
                    __builtin_nontemporal_store(acc[mi][ns][r] + bv,
                                                &out[(size_t)row * V_ + col]);
                }
            }
        }
}

// ---------------- host ----------------

extern "C" void kernel_launch(void* const* d_in, const int* in_sizes, int n_in,
                              void* d_out, int out_size, void* d_ws, size_t ws_size,
                              hipStream_t stream)
{
    const int*   x    = (const int*)d_in[0];
    const float* h0   = (const float*)d_in[1];
    const float* h1   = (const float*)d_in[2];
    const float* h2   = (const float*)d_in[3];
    const float* c0   = (const float*)d_in[4];
    const float* c1   = (const float*)d_in[5];
    const float* c2   = (const float*)d_in[6];
    const float* emb  = (const float*)d_in[7];
    const float* Wih0 = (const float*)d_in[8];
    const float* Whh0 = (const float*)d_in[9];
    const float* bih0 = (const float*)d_in[10];
    const float* bhh0 = (const float*)d_in[11];
    const float* Wih1 = (const float*)d_in[12];
    const float* Whh1 = (const float*)d_in[13];
    const float* bih1 = (const float*)d_in[14];
    const float* bhh1 = (const float*)d_in[15];
    const float* Wih2 = (const float*)d_in[16];
    const float* Whh2 = (const float*)d_in[17];
    const float* bih2 = (const float*)d_in[18];
    const float* bhh2 = (const float*)d_in[19];
    const float* decW = (const float*)d_in[20];
    const float* decb = (const float*)d_in[21];

    char* wsb = (char*)d_ws;
    size_t off = 0;
    auto alloc = [&](size_t bytes) -> void* {
        void* ptr = wsb + off;
        off = (off + bytes + 255) & ~(size_t)255;
        return ptr;
    };

    bf16* W0i = (bf16*)alloc((size_t)4608 * KU * 2);
    bf16* W1i = (bf16*)alloc((size_t)4608 * KU * 2);
    bf16* W2i = (bf16*)alloc((size_t)1600 * KU * 2);
    bf16* Wdc = (bf16*)alloc((size_t)V_ * KD * 2);
    float* b0i = (float*)alloc(4608 * 4);
    float* b1i = (float*)alloc(4608 * 4);
    float* b2i = (float*)alloc(1600 * 4);
    bf16* XEf = (bf16*)alloc((size_t)T_ * XET * 2);
    bf16* H0f0 = (bf16*)alloc((size_t)B_ * H_ * 2);
    bf16* H0f1 = (bf16*)alloc((size_t)B_ * H_ * 2);
    bf16* H1f0 = (bf16*)alloc((size_t)B_ * H_ * 2);
    bf16* H1f1 = (bf16*)alloc((size_t)B_ * H_ * 2);
    bf16* H2f0 = (bf16*)alloc((size_t)B_ * XW * 2);
    bf16* H2f1 = (bf16*)alloc((size_t)B_ * XW * 2);
    float* c0b = (float*)alloc((size_t)B_ * H_ * 4);
    float* c1b = (float*)alloc((size_t)B_ * H_ * 4);
    float* c2b = (float*)alloc((size_t)B_ * E_ * 4);
    bf16* OUTB = (bf16*)alloc((size_t)T_ * B_ * XW * 2);
    int* gbar = (int*)alloc(2048);   // flags[0..168]; gen8 at +256 (8 x 64B)

    auto cdiv = [](long a, long b) { return (int)((a + b - 1) / b); };

    prep_wint8<<<cdiv(4608L * (KU/8), 256), 256, 0, stream>>>(Wih0, 400,  Whh0, 416,  1152, 1152, W0i, 4608L * (KU/8));
    prep_wint8<<<cdiv(4608L * (KU/8), 256), 256, 0, stream>>>(Wih1, 1152, Whh1, 1152, 1152, 1152, W1i, 4608L * (KU/8));
    prep_wint8<<<cdiv(1600L * (KU/8), 256), 256, 0, stream>>>(Wih2, 1152, Whh2, 1152, 400,  400,  W2i, 1600L * (KU/8));
    prep_wcat8<<<cdiv((long)V_ * (KD/8), 256), 256, 0, stream>>>(decW, 400, Wdc, KD, (long)V_ * (KD/8));
    bias_all<<<cdiv(10816, 256), 256, 0, stream>>>(bih0, bhh0, bih1, bhh1, bih2, bhh2, b0i, b1i, b2i);
    gather_xef8<<<cdiv((long)T_ * B_ * (XW/8), 256), 256, 0, stream>>>(x, emb, XEf);

    hipMemsetAsync(OUTB, 0, (size_t)T_ * B_ * XW * 2, stream);

    init_states<<<cdiv(B_ * H_, 256), 256, 0, stream>>>(
        h0, h1, h2, c0, c1, c2,
        H0f1, H1f1, H2f0, H2f1, c0b, c1b, c2b, gbar);

    {
        int* flags = gbar;
        int* gen8  = gbar + 256;
        void* args[] = {
            (void*)&XEf, (void*)&W0i, (void*)&W1i, (void*)&W2i,
            (void*)&b0i, (void*)&b1i, (void*)&b2i,
            (void*)&H0f0, (void*)&H0f1, (void*)&H1f0, (void*)&H1f1,
            (void*)&H2f0, (void*)&H2f1,
            (void*)&c0b, (void*)&c1b, (void*)&c2b, (void*)&OUTB,
            (void*)&flags, (void*)&gen8
        };
        hipLaunchCooperativeKernel((void*)awd_persistent, dim3(NBLK), dim3(512),
                                   args, 0, stream);
    }

    decoder<<<dim3(80 * 128), 256, 0, stream>>>(OUTB, Wdc, decb, (float*)d_out);
}

// Round 20
// 3045.206 us; speedup vs baseline: 1.0692x; 1.0692x over previous
//
#include <hip/hip_runtime.h>
#include <hip/hip_bf16.h>

typedef __hip_bfloat16 bf16;
typedef __attribute__((ext_vector_type(8))) short short8;
typedef __attribute__((ext_vector_type(4))) float f32x4;

#define T_ 256
#define B_ 64
#define V_ 10000
#define E_ 400
#define H_ 1152
#define KU 2304      // uniform padded K for weight buffers (72 kt of 32)
#define XW 416       // padded embedding width (13 kt)
#define KD 416       // decoder K (padded)
#define XET (XW*B_)  // shorts per timestep in frag-major
#define NBLK 169

#define MFMA16 __builtin_amdgcn_mfma_f32_16x16x32_bf16
#define ATL(p) __hip_atomic_load((p), __ATOMIC_RELAXED, __HIP_MEMORY_SCOPE_AGENT)
#define ATS(p, v) __hip_atomic_store((p), (v), __ATOMIC_RELAXED, __HIP_MEMORY_SCOPE_AGENT)
#define PIN(x) asm volatile("" : "+v"(x))

// ---------------- prep kernels ----------------

// 8-wide gate-interleaved weight prep (region boundaries all %8 == 0)
__global__ __launch_bounds__(256) void prep_wint8(
    const float* __restrict__ s1, int w1,
    const float* __restrict__ s2, int off2, int w2, int Hl,
    bf16* __restrict__ dst, long total8)
{
    long i = (long)blockIdx.x * 256 + threadIdx.x;
    if (i >= total8) return;
    const int KB = KU / 8;
    int kb = (int)(i % KB) * 8;
    long r = i / KB;
    int hcol = (int)(r >> 2), gate = (int)(r & 3);
    long srow = (long)gate * Hl + hcol;
    const float* src = nullptr;
    if (kb < w1) src = s1 + srow * w1 + kb;
    else if (kb >= off2 && kb < off2 + w2) src = s2 + srow * w2 + (kb - off2);
    short8 v;
    #pragma unroll
    for (int j = 0; j < 8; ++j) {
        bf16 b = __float2bfloat16(src ? src[j] : 0.f);
        unsigned short us; __builtin_memcpy(&us, &b, 2);
        v[j] = (short)us;
    }
    *(short8*)(dst + r * KU + kb) = v;
}

// 8-wide decoder weight prep (w1=400 multiple of 8)
__global__ __launch_bounds__(256) void prep_wcat8(
    const float* __restrict__ s1, int w1,
    bf16* __restrict__ dst, int Ktot, long total8)
{
    long i = (long)blockIdx.x * 256 + threadIdx.x;
    if (i >= total8) return;
    int KB = Ktot / 8;
    int kb = (int)(i % KB) * 8;
    long n = i / KB;
    const float* src = (kb < w1) ? s1 + n * w1 + kb : nullptr;
    short8 v;
    #pragma unroll
    for (int j = 0; j < 8; ++j) {
        bf16 b = __float2bfloat16(src ? src[j] : 0.f);
        unsigned short us; __builtin_memcpy(&us, &b, 2);
        v[j] = (short)us;
    }
    *(short8*)(dst + n * Ktot + kb) = v;
}

// fused bias prep: [0,4608) -> b0i, [4608,9216) -> b1i, [9216,10816) -> b2i
__global__ __launch_bounds__(256) void bias_all(
    const float* __restrict__ bih0, const float* __restrict__ bhh0,
    const float* __restrict__ bih1, const float* __restrict__ bhh1,
    const float* __restrict__ bih2, const float* __restrict__ bhh2,
    float* __restrict__ b0i, float* __restrict__ b1i, float* __restrict__ b2i)
{
    int i = blockIdx.x * 256 + threadIdx.x;
    if (i < 4608) {
        int hcol = i >> 2, g = i & 3;
        b0i[i] = bih0[g * 1152 + hcol] + bhh0[g * 1152 + hcol];
    } else if (i < 9216) {
        int r = i - 4608, hcol = r >> 2, g = r & 3;
        b1i[r] = bih1[g * 1152 + hcol] + bhh1[g * 1152 + hcol];
    } else if (i < 10816) {
        int r = i - 9216, hcol = r >> 2, g = r & 3;
        b2i[r] = bih2[g * 400 + hcol] + bhh2[g * 400 + hcol];
    }
}

// 8-wide embeddings -> frag-major bf16 (k&7 consecutive in dst: 16B stores)
__global__ __launch_bounds__(256) void gather_xef8(
    const int* __restrict__ x, const float* __restrict__ emb,
    bf16* __restrict__ XEf)
{
    long i = (long)blockIdx.x * 256 + threadIdx.x;
    const long total8 = (long)T_ * B_ * (XW / 8);
    if (i >= total8) return;
    const int KB = XW / 8;
    int kb = (int)(i % KB) * 8;
    int b = (int)((i / KB) % B_);
    int t = (int)(i / ((long)KB * B_));
    const float* src = (kb < E_) ? emb + (long)x[t * B_ + b] * E_ + kb : nullptr;
    short8 v;
    #pragma unroll
    for (int j = 0; j < 8; ++j) {
        bf16 bb = __float2bfloat16(src ? src[j] : 0.f);
        unsigned short us; __builtin_memcpy(&us, &bb, 2);
        v[j] = (short)us;
    }
    *(short8*)(XEf + (long)t * XET + (((kb >> 3) * 64 + b) << 3)) = v;
}

// fused state init: frag-major h copies, plain c copies, H2 pad zero, gbar zero
__global__ __launch_bounds__(256) void init_states(
    const float* __restrict__ h0, const float* __restrict__ h1,
    const float* __restrict__ h2,
    const float* __restrict__ c0, const float* __restrict__ c1,
    const float* __restrict__ c2,
    bf16* __restrict__ H0f1, bf16* __restrict__ H1f1,
    bf16* __restrict__ H2f0, bf16* __restrict__ H2f1,
    float* __restrict__ c0b, float* __restrict__ c1b, float* __restrict__ c2b,
    int* __restrict__ gbar)
{
    int i = blockIdx.x * 256 + threadIdx.x;
    if (i < B_ * H_) {
        int k = ((i >> 9) << 3) | (i & 7);
        int b = (i >> 3) & 63;
        H0f1[i] = __float2bfloat16(h0[(long)b * H_ + k]);
        H1f1[i] = __float2bfloat16(h1[(long)b * H_ + k]);
        c0b[i] = c0[i];
        c1b[i] = c1[i];
    }
    if (i < B_ * XW) {
        int k = ((i >> 9) << 3) | (i & 7);
        int b = (i >> 3) & 63;
        H2f1[i] = (k < E_) ? __float2bfloat16(h2[(long)b * E_ + k])
                           : __float2bfloat16(0.f);
        H2f0[i] = __float2bfloat16(0.f);
    }
    if (i < B_ * E_) c2b[i] = c2[i];
    if (i < 512) gbar[i] = 0;
}

// ---- two-level grid barrier with 8-way replicated gen publication ----
__device__ __forceinline__ void grid_bar(int* flags, int* gen8, int phase) {
    asm volatile("s_waitcnt vmcnt(0)" ::: "memory");  // per-wave: stores drained
    __syncthreads();
    if (blockIdx.x == 0) {
        if (threadIdx.x < 64) {
            const int ln = threadIdx.x;
            if (ln == 0) ATS(&flags[0], phase);
            for (;;) {
                int f0 = (ln       < NBLK) ? ATL(&flags[ln])       : phase;
                int f1 = (ln + 64  < NBLK) ? ATL(&flags[ln + 64])  : phase;
                int f2 = (ln + 128 < NBLK) ? ATL(&flags[ln + 128]) : phase;
                if (__all(f0 >= phase && f1 >= phase && f2 >= phase)) break;
                __builtin_amdgcn_s_sleep(1);
            }
            if (ln < 8) ATS(&gen8[ln * 16], phase);
            if (ln == 0)
                __builtin_amdgcn_fence(__ATOMIC_ACQUIRE, "agent");  // inv L1/L2
        }
    } else {
        if (threadIdx.x == 0) {
            ATS(&flags[blockIdx.x], phase);
            while (ATL(&gen8[(blockIdx.x & 7) * 16]) < phase)
                __builtin_amdgcn_s_sleep(1);
            __builtin_amdgcn_fence(__ATOMIC_ACQUIRE, "agent");      // inv L1/L2
        }
    }
    __syncthreads();
    asm volatile("" ::: "memory");
}

// ------------- weight-stationary persistent LSTM (R14/R18 structure) -------------
struct Frag4 { short8 f0, f1, f2, f3; };

__global__ __launch_bounds__(512, 2) void awd_persistent(
    const bf16* __restrict__ XEf,
    const bf16* __restrict__ W0, const bf16* __restrict__ W1, const bf16* __restrict__ W2,
    const float* __restrict__ b0, const float* __restrict__ b1, const float* __restrict__ b2,
    bf16* H0f0, bf16* H0f1, bf16* H1f0, bf16* H1f1, bf16* H2f0, bf16* H2f1,
    float* c0, float* c1, float* c2, bf16* OUTB,
    int* flags, int* gen8)
{
    __shared__ float gsm[2][4][64][65];     // 133 KB: two halves, no RMW pass
    __shared__ unsigned short hsm[64][24];  // h transpose buffer
    const int bid = blockIdx.x;
    const int tid = threadIdx.x;
    const int lane = tid & 63;
    const int w8 = tid >> 6;              // K-slice index 0..7
    const int lh = lane >> 4, l15 = lane & 15;
    const int boff8 = (lh * 64 + l15) * 8;

    int layer, grp;
    if (bid < 72)       { layer = 1; grp = bid; }
    else if (bid < 144) { layer = 0; grp = bid - 72; }
    else                { layer = 2; grp = bid - 144; }

    const bf16* Wp  = (layer == 0) ? W0 : (layer == 1) ? W1 : W2;
    const float* bias = (layer == 0) ? b0 : (layer == 1) ? b1 : b2;
    const float* cbuf = (layer == 0) ? c0 : (layer == 1) ? c1 : c2;
    const int Hl  = (layer == 2) ? 400 : 1152;
    const int bkt = (layer == 0) ? 13 : 36;   // kt where A switches A1 -> A2
    const int nkt = (layer == 1) ? 72 : 49;   // real kt count
    const int KT  = (layer == 1) ? 9  : 7;    // u-steps per wave
    const int kbase = w8 * KT;

    // ---- weights into registers (once), then PIN so they stay resident ----
    short8 wreg[9][4];
    #pragma unroll
    for (int u = 0; u < 9; ++u)
        if (u < KT) {
            #pragma unroll
            for (int rt = 0; rt < 4; ++rt) {
                int row = grp * 64 + rt * 16 + l15;
                int k   = (kbase + u) * 32 + lh * 8;
                wreg[u][rt] = *(const short8*)(Wp + (long)row * KU + k);
                PIN(wreg[u][rt]);
            }
        }

    float myb[2][4];
    #pragma unroll
    for (int e = 0; e < 2; ++e)
        #pragma unroll
        for (int g = 0; g < 4; ++g)
            myb[e][g] = bias[grp * 64 + (w8 + e * 8) * 4 + g];

    float creg[2];
    #pragma unroll
    for (int e = 0; e < 2; ++e)
        creg[e] = cbuf[(long)lane * Hl + grp * 16 + w8 + e * 8];

    for (int s = -1; s <= 256; ++s) {
        bool active = (layer == 0) ? (s <= 254)
                    : (layer == 1) ? (s >= 0 && s <= 255)
                                   : (s >= 1);
        if (active) {
            const int p = s & 1, q = p ^ 1;
            const bf16 *A1, *A2; bf16* hfW; bf16* ob = nullptr;
            if (layer == 0) {
                A1 = XEf + (long)(s + 1) * XET;
                A2 = p ? H0f1 : H0f0;
                hfW = q ? H0f1 : H0f0;
            } else if (layer == 1) {
                A1 = p ? H0f1 : H0f0;
                A2 = q ? H1f1 : H1f0;
                hfW = p ? H1f1 : H1f0;
            } else {
                A1 = q ? H1f1 : H1f0;
                A2 = p ? H2f1 : H2f0;
                hfW = q ? H2f1 : H2f0;
                ob = OUTB + (long)(s - 1) * B_ * XW;
            }

            // plain CACHED frag load; frags at +0,+128,+256,+384 bf16 elements
            auto loadf = [&](int u) -> Frag4 {
                const int ktg = kbase + u;
                const bf16* src; int ktL;
                if (ktg < bkt)      { src = A1; ktL = ktg; }
                else if (ktg < nkt) { src = A2; ktL = ktg - bkt; }
                else                { src = A1; ktL = 0; }   // pad: zero weights
                const bf16* pB = src + ktL * 2048 + boff8;
                Frag4 r;
                r.f0 = *(const short8*)(pB);
                r.f1 = *(const short8*)(pB + 128);
                r.f2 = *(const short8*)(pB + 256);
                r.f3 = *(const short8*)(pB + 384);
                return r;
            };

            f32x4 acc[4][4];
            #pragma unroll
            for (int rt = 0; rt < 4; ++rt)
                #pragma unroll
                for (int m = 0; m < 4; ++m)
                    acc[rt][m] = (f32x4){0.f, 0.f, 0.f, 0.f};

            auto domfma = [&](int u, const Frag4& f) {
                #pragma unroll
                for (int rt = 0; rt < 4; ++rt) {
                    acc[rt][0] = MFMA16(wreg[u][rt], f.f0, acc[rt][0], 0, 0, 0);
                    acc[rt][1] = MFMA16(wreg[u][rt], f.f1, acc[rt][1], 0, 0, 0);
                    acc[rt][2] = MFMA16(wreg[u][rt], f.f2, acc[rt][2], 0, 0, 0);
                    acc[rt][3] = MFMA16(wreg[u][rt], f.f3, acc[rt][3], 0, 0, 0);
                }
            };

            #pragma unroll
            for (int u = 0; u < 9; ++u)
                if (u < KT) {
                    Frag4 f = loadf(u);
                    domfma(u, f);
                }

            // dual-buffer merge: all 8 waves write in parallel
            #pragma unroll
            for (int rt = 0; rt < 4; ++rt)
                #pragma unroll
                for (int m = 0; m < 4; ++m)
                    #pragma unroll
                    for (int r = 0; r < 4; ++r)
                        gsm[w8 >> 2][w8 & 3][rt * 16 + lh * 4 + r][m * 16 + l15] = acc[rt][m][r];
            __syncthreads();

            // nonlinearity: 16 cols x 64 batch, 2 per thread; h -> LDS transpose
            #pragma unroll
            for (int e = 0; e < 2; ++e) {
                int b = lane;
                int cl = w8 + e * 8;
                float gv[4];
                #pragma unroll
                for (int g = 0; g < 4; ++g) {
                    float v = myb[e][g];
                    #pragma unroll
                    for (int kq = 0; kq < 4; ++kq)
                        v += gsm[0][kq][cl * 4 + g][b] + gsm[1][kq][cl * 4 + g][b];
                    gv[g] = v;
                }
                float c_old = creg[e];
                float i_s = 1.f / (1.f + expf(-gv[0]));
                float f_s = 1.f / (1.f + expf(-gv[1]));
                float o_s = 1.f / (1.f + expf(-gv[3]));
                float c_new = f_s * c_old + i_s * tanhf(gv[2]);
                float hval = o_s * tanhf(c_new);
                creg[e] = c_new;
                bf16 hb = __float2bfloat16(hval);
                unsigned short hbits;
                __builtin_memcpy(&hbits, &hb, 2);
                hsm[b][cl] = hbits;
            }
            __syncthreads();

            // coalesced store-out: waves 0/1 -> h frag-major (write-through,
            // 16B/lane); wave 2 -> OUTB
            if (w8 < 2) {
                unsigned long long v0, v1;
                __builtin_memcpy(&v0, &hsm[lane][w8 * 8], 8);
                __builtin_memcpy(&v1, &hsm[lane][w8 * 8 + 4], 8);
                unsigned long long* qp =
                    (unsigned long long*)(hfW + (((long)grp * 2 + w8) * 64 + lane) * 8);
                ATS(qp, v0);
                ATS(qp + 1, v1);
            } else if (w8 == 2 && layer == 2) {
                short8 v0 = *(const short8*)&hsm[lane][0];
                short8 v1 = *(const short8*)&hsm[lane][8];
                *(short8*)(ob + (long)lane * XW + grp * 16) = v0;
                *(short8*)(ob + (long)lane * XW + grp * 16 + 8) = v1;
            }
        }
        grid_bar(flags, gen8, s + 2);
    }
}

// ---------------- decoder GEMM: 128x128 per WG, XCD N-stripe swizzle ----------------
__global__ __launch_bounds__(256) void decoder(
    const bf16* __restrict__ A, const bf16* __restrict__ W,
    const float* __restrict__ bias, float* __restrict__ out)
{
    const int id = blockIdx.x;
    const int xcd = id & 7;
    const int local = id >> 3;
    const int n_blk = xcd * 10 + local % 10;
    const int m_blk = local / 10;
    if (n_blk >= 79) return;

    const int tid = threadIdx.x;
    const int lane = tid & 63;
    const int w = tid >> 6;
    const int mw = w >> 1, nw = w & 1;
    const int n0 = n_blk * 128 + nw * 64;
    const int m0 = m_blk * 128 + mw * 64;
    const int c16 = lane & 15;
    const int kg = lane >> 4;

    f32x4 acc[4][4];
    #pragma unroll
    for (int mi = 0; mi < 4; ++mi)
        #pragma unroll
        for (int ns = 0; ns < 4; ++ns)
            acc[mi][ns] = (f32x4){0.f, 0.f, 0.f, 0.f};

    int nrow[4];
    #pragma unroll
    for (int ns = 0; ns < 4; ++ns) {
        int n = n0 + ns * 16 + c16;
        nrow[ns] = (n < V_) ? n : (V_ - 1);
    }

    const bf16* arow = A + (long)(m0 + c16) * KD + kg * 8;
    #pragma unroll
    for (int kt = 0; kt < 13; ++kt) {
        short8 af[4], bf[4];
        #pragma unroll
        for (int mi = 0; mi < 4; ++mi)
            af[mi] = *(const short8*)(arow + (long)mi * 16 * KD + kt * 32);
        #pragma unroll
        for (int ns = 0; ns < 4; ++ns)
            bf[ns] = *(const short8*)(W + (long)nrow[ns] * KD + kt * 32 + kg * 8);
        #pragma unroll
        for (int mi = 0; mi < 4; ++mi)
            #pragma unroll
            for (int ns = 0; ns < 4; ++ns)
                acc[mi][ns] = MFMA16(af[mi], bf[ns], acc[mi][ns], 0, 0, 0);
    }

    #pragma unroll
    for (int mi = 0; mi < 4; ++mi)
        #pragma unroll
        for (int ns = 0; ns < 4; ++ns) {
            int col = n0 + ns * 16 + c16;
            if (col < V_) {
                float bv = bias[col];
                #pragma unroll
                for (int r = 0; r < 4; ++r) {
                    int row = m0 + mi * 16 + kg * 4 + r;
                    __builtin_nontemporal_store(acc[mi][ns][r] + bv,
                                                &out[(size_t)row * V_ + col]);
                }
            }
        }
}

// ---------------- host ----------------

extern "C" void kernel_launch(void* const* d_in, const int* in_sizes, int n_in,
                              void* d_out, int out_size, void* d_ws, size_t ws_size,
                              hipStream_t stream)
{
    const int*   x    = (const int*)d_in[0];
    const float* h0   = (const float*)d_in[1];
    const float* h1   = (const float*)d_in[2];
    const float* h2   = (const float*)d_in[3];
    const float* c0   = (const float*)d_in[4];
    const float* c1   = (const float*)d_in[5];
    const float* c2   = (const float*)d_in[6];
    const float* emb  = (const float*)d_in[7];
    const float* Wih0 = (const float*)d_in[8];
    const float* Whh0 = (const float*)d_in[9];
    const float* bih0 = (const float*)d_in[10];
    const float* bhh0 = (const float*)d_in[11];
    const float* Wih1 = (const float*)d_in[12];
    const float* Whh1 = (const float*)d_in[13];
    const float* bih1 = (const float*)d_in[14];
    const float* bhh1 = (const float*)d_in[15];
    const float* Wih2 = (const float*)d_in[16];
    const float* Whh2 = (const float*)d_in[17];
    const float* bih2 = (const float*)d_in[18];
    const float* bhh2 = (const float*)d_in[19];
    const float* decW = (const float*)d_in[20];
    const float* decb = (const float*)d_in[21];

    char* wsb = (char*)d_ws;
    size_t off = 0;
    auto alloc = [&](size_t bytes) -> void* {
        void* ptr = wsb + off;
        off = (off + bytes + 255) & ~(size_t)255;
        return ptr;
    };

    bf16* W0i = (bf16*)alloc((size_t)4608 * KU * 2);
    bf16* W1i = (bf16*)alloc((size_t)4608 * KU * 2);
    bf16* W2i = (bf16*)alloc((size_t)1600 * KU * 2);
    bf16* Wdc = (bf16*)alloc((size_t)V_ * KD * 2);
    float* b0i = (float*)alloc(4608 * 4);
    float* b1i = (float*)alloc(4608 * 4);
    float* b2i = (float*)alloc(1600 * 4);
    bf16* XEf = (bf16*)alloc((size_t)T_ * XET * 2);
    bf16* H0f0 = (bf16*)alloc((size_t)B_ * H_ * 2);
    bf16* H0f1 = (bf16*)alloc((size_t)B_ * H_ * 2);
    bf16* H1f0 = (bf16*)alloc((size_t)B_ * H_ * 2);
    bf16* H1f1 = (bf16*)alloc((size_t)B_ * H_ * 2);
    bf16* H2f0 = (bf16*)alloc((size_t)B_ * XW * 2);
    bf16* H2f1 = (bf16*)alloc((size_t)B_ * XW * 2);
    float* c0b = (float*)alloc((size_t)B_ * H_ * 4);
    float* c1b = (float*)alloc((size_t)B_ * H_ * 4);
    float* c2b = (float*)alloc((size_t)B_ * E_ * 4);
    bf16* OUTB = (bf16*)alloc((size_t)T_ * B_ * XW * 2);
    int* gbar = (int*)alloc(2048);   // flags[0..168]; gen8 at +256 (8 x 64B)

    auto cdiv = [](long a, long b) { return (int)((a + b - 1) / b); };

    prep_wint8<<<cdiv(4608L * (KU/8), 256), 256, 0, stream>>>(Wih0, 400,  Whh0, 416,  1152, 1152, W0i, 4608L * (KU/8));
    prep_wint8<<<cdiv(4608L * (KU/8), 256), 256, 0, stream>>>(Wih1, 1152, Whh1, 1152, 1152, 1152, W1i, 4608L * (KU/8));
    prep_wint8<<<cdiv(1600L * (KU/8), 256), 256, 0, stream>>>(Wih2, 1152, Whh2, 1152, 400,  400,  W2i, 1600L * (KU/8));
    prep_wcat8<<<cdiv((long)V_ * (KD/8), 256), 256, 0, stream>>>(decW, 400, Wdc, KD, (long)V_ * (KD/8));
    bias_all<<<cdiv(10816, 256), 256, 0, stream>>>(bih0, bhh0, bih1, bhh1, bih2, bhh2, b0i, b1i, b2i);
    gather_xef8<<<cdiv((long)T_ * B_ * (XW/8), 256), 256, 0, stream>>>(x, emb, XEf);

    hipMemsetAsync(OUTB, 0, (size_t)T_ * B_ * XW * 2, stream);

    init_states<<<cdiv(B_ * H_, 256), 256, 0, stream>>>(
        h0, h1, h2, c0, c1, c2,
        H0f1, H1f1, H2f0, H2f1, c0b, c1b, c2b, gbar);

    {
        int* flags = gbar;
        int* gen8  = gbar + 256;
        void* args[] = {
            (void*)&XEf, (void*)&W0i, (void*)&W1i, (void*)&W2i,
            (void*)&b0i, (void*)&b1i, (void*)&b2i,
            (void*)&H0f0, (void*)&H0f1, (void*)&H1f0, (void*)&H1f1,
            (void*)&H2f0, (void*)&H2f1,
            (void*)&c0b, (void*)&c1b, (void*)&c2b, (void*)&OUTB,
            (void*)&flags, (void*)&gen8
        };
        hipLaunchCooperativeKernel((void*)awd_persistent, dim3(NBLK), dim3(512),
                                   args, 0, stream);
    }

    decoder<<<dim3(80 * 128), 256, 0, stream>>>(OUTB, Wdc, decb, (float*)d_out);
}